// Round 4
// baseline (63534.857 us; speedup 1.0000x reference)
//
#include <hip/hip_runtime.h>
#include <math.h>

#define D 256
#define SEQ 1000
#define NB 32
#define PATCH 160
#define NL 6
#define M_TOTAL (NB * SEQ)   // 32000
#define G3 (3 * D)           // 768

typedef __attribute__((ext_vector_type(2))) _Float16 half2_t;
typedef __attribute__((ext_vector_type(4))) _Float16 half4_t;
typedef __attribute__((ext_vector_type(8))) _Float16 half8_t;

__device__ __forceinline__ float gelu_exact(float v) {
    return 0.5f * v * (1.0f + erff(v * 0.70710678118654752440f));
}

#if defined(__has_builtin) && __has_builtin(__builtin_amdgcn_fdot2)
__device__ __forceinline__ float fdot2_(half2_t a, half2_t b, float c) {
    return __builtin_amdgcn_fdot2(a, b, c, false);
}
#else
__device__ __forceinline__ float fdot2_(half2_t a, half2_t b, float c) {
    return fmaf((float)a.x, (float)b.x, fmaf((float)a.y, (float)b.y, c));
}
#endif

__device__ __forceinline__ half2_t u2h(unsigned u) {
    return __builtin_bit_cast(half2_t, u);
}

// ---------------------------------------------------------------------------
// Kernel 0: fp32 -> fp16 weight conversion (all 6 layers of w_hh, once)
// ---------------------------------------------------------------------------
__global__ __launch_bounds__(256) void cvt_whh_fp16(
    const float* __restrict__ src, _Float16* __restrict__ dst)
{
    int i = blockIdx.x * 256 + threadIdx.x;   // grid sized exactly
    float4 v = ((const float4*)src)[i];
    half4_t o;
    o.x = (_Float16)v.x; o.y = (_Float16)v.y;
    o.z = (_Float16)v.z; o.w = (_Float16)v.w;
    ((half4_t*)dst)[i] = o;
}

// ---------------------------------------------------------------------------
// Kernel 1: conv patchify GEMM + exact GELU + pos_emb add
// ---------------------------------------------------------------------------
__global__ __launch_bounds__(256) void conv_gelu_pos(
    const float* __restrict__ wav, const float* __restrict__ cw,
    const float* __restrict__ pos, float* __restrict__ x)
{
    __shared__ float As[64][33];
    __shared__ float Bs[32][65];
    const int m0 = blockIdx.x * 64;
    const int n0 = blockIdx.y * 64;
    const int tid = threadIdx.x;
    const int tx = tid & 15;      // 0..15 -> n
    const int ty = tid >> 4;      // 0..15 -> m
    float acc[4][4] = {};

    for (int kc = 0; kc < PATCH; kc += 32) {
        for (int p = 0; p < 8; ++p) {
            int mr = p * 8 + (tid >> 5);
            int kk = tid & 31;
            int m = m0 + mr;
            int b = m / SEQ, s = m % SEQ;
            As[mr][kk] = wav[(size_t)b * 160000 + (size_t)s * PATCH + kc + kk];
        }
        for (int p = 0; p < 8; ++p) {
            int kr = p * 4 + (tid >> 6);
            int nn = tid & 63;
            Bs[kr][nn] = cw[(size_t)(kc + kr) * D + n0 + nn];
        }
        __syncthreads();
        #pragma unroll
        for (int kk = 0; kk < 32; ++kk) {
            float a[4], bb[4];
            #pragma unroll
            for (int i = 0; i < 4; ++i) a[i] = As[ty * 4 + i][kk];
            #pragma unroll
            for (int j = 0; j < 4; ++j) bb[j] = Bs[kk][tx * 4 + j];
            #pragma unroll
            for (int i = 0; i < 4; ++i)
                #pragma unroll
                for (int j = 0; j < 4; ++j)
                    acc[i][j] = fmaf(a[i], bb[j], acc[i][j]);
        }
        __syncthreads();
    }
    #pragma unroll
    for (int i = 0; i < 4; ++i) {
        int m = m0 + ty * 4 + i;
        int s = m % SEQ;
        int n = n0 + tx * 4;
        float4 v;
        v.x = gelu_exact(acc[i][0]) + pos[(size_t)s * D + n + 0];
        v.y = gelu_exact(acc[i][1]) + pos[(size_t)s * D + n + 1];
        v.z = gelu_exact(acc[i][2]) + pos[(size_t)s * D + n + 2];
        v.w = gelu_exact(acc[i][3]) + pos[(size_t)s * D + n + 3];
        *(float4*)&x[(size_t)m * D + n] = v;
    }
}

// ---------------------------------------------------------------------------
// Kernel 2: per-row mean / rstd
// ---------------------------------------------------------------------------
__global__ __launch_bounds__(64) void row_stats(
    const float* __restrict__ x, float* __restrict__ st)
{
    const int m = blockIdx.x;
    const int t = threadIdx.x;
    const float* r = x + (size_t)m * D;
    float s = 0.f, q = 0.f;
    #pragma unroll
    for (int i = 0; i < 4; ++i) {
        float v = r[t + 64 * i];
        s += v;
        q += v * v;
    }
    #pragma unroll
    for (int o = 32; o > 0; o >>= 1) {
        s += __shfl_down(s, o);
        q += __shfl_down(q, o);
    }
    if (t == 0) {
        float mu = s * (1.f / 256.f);
        float var = q * (1.f / 256.f) - mu * mu;
        st[2 * m]     = mu;
        st[2 * m + 1] = rsqrtf(var + 1e-5f);
    }
}

// ---------------------------------------------------------------------------
// Kernel 3: fused LN + input-projection GEMM
// ---------------------------------------------------------------------------
__global__ __launch_bounds__(256) void ln_xp_gemm(
    const float* __restrict__ x, const float* __restrict__ st,
    const float* __restrict__ lnsc, const float* __restrict__ lnbi,
    const float* __restrict__ wih, const float* __restrict__ bih,
    float* __restrict__ xp)
{
    __shared__ float As[64][33];
    __shared__ float Bs[32][65];
    __shared__ float sc[D], bi[D];
    const int m0 = blockIdx.x * 64;
    const int n0 = blockIdx.y * 64;
    const int tid = threadIdx.x;
    const int tx = tid & 15;
    const int ty = tid >> 4;
    sc[tid] = lnsc[tid];
    bi[tid] = lnbi[tid];
    float acc[4][4] = {};

    for (int kc = 0; kc < D; kc += 32) {
        for (int p = 0; p < 8; ++p) {
            int mr = p * 8 + (tid >> 5);
            int kk = tid & 31;
            int m = m0 + mr;
            float mu = st[2 * m], rs = st[2 * m + 1];
            float v = x[(size_t)m * D + kc + kk];
            As[mr][kk] = (v - mu) * rs * sc[kc + kk] + bi[kc + kk];
        }
        for (int p = 0; p < 8; ++p) {
            int nr = p * 8 + (tid >> 5);
            int kk = tid & 31;
            Bs[kk][nr] = wih[(size_t)(n0 + nr) * D + kc + kk];
        }
        __syncthreads();
        #pragma unroll
        for (int kk = 0; kk < 32; ++kk) {
            float a[4], bb[4];
            #pragma unroll
            for (int i = 0; i < 4; ++i) a[i] = As[ty * 4 + i][kk];
            #pragma unroll
            for (int j = 0; j < 4; ++j) bb[j] = Bs[kk][tx * 4 + j];
            #pragma unroll
            for (int i = 0; i < 4; ++i)
                #pragma unroll
                for (int j = 0; j < 4; ++j)
                    acc[i][j] = fmaf(a[i], bb[j], acc[i][j]);
        }
        __syncthreads();
    }
    #pragma unroll
    for (int i = 0; i < 4; ++i) {
        int m = m0 + ty * 4 + i;
        int n = n0 + tx * 4;
        float4 v;
        v.x = acc[i][0] + bih[n + 0];
        v.y = acc[i][1] + bih[n + 1];
        v.z = acc[i][2] + bih[n + 2];
        v.w = acc[i][3] + bih[n + 3];
        *(float4*)&xp[(size_t)m * G3 + n] = v;
    }
}

// ---------------------------------------------------------------------------
// Kernel 4: persistent-register GRU recurrence.
// One block per batch (32 blocks), 768 threads = 12 waves (3/SIMD, cap 170
// VGPR via __launch_bounds__(768,3)).
// Thread g holds w_hh row g as 32 NAMED uint4 variables (VReg_128 tuples;
// every access is a constant field select -> cannot be scratch-demoted the
// way indexed arrays / 1024-bit vectors were in rounds 1-2).
// ---------------------------------------------------------------------------
#define REP32(M) M(0) M(1) M(2) M(3) M(4) M(5) M(6) M(7) \
                 M(8) M(9) M(10) M(11) M(12) M(13) M(14) M(15) \
                 M(16) M(17) M(18) M(19) M(20) M(21) M(22) M(23) \
                 M(24) M(25) M(26) M(27) M(28) M(29) M(30) M(31)

__global__ __launch_bounds__(768, 3) void gru_scan_persist(
    const float* __restrict__ xp, const _Float16* __restrict__ whh16,
    const float* __restrict__ bhh, float* __restrict__ x)
{
    __shared__ float gates[G3];
    __shared__ float xn_s[D];
    __shared__ float hf[D];
    __shared__ __align__(16) _Float16 h16[D];

    const int g = threadIdx.x;   // 0..767 gate-row
    const int b = blockIdx.x;

    // ---- preload weights: row g as 32 named uint4 ----
    const uint4* wrow = (const uint4*)(whh16 + (size_t)g * D);
#define DECLW(n) uint4 W##n = wrow[n];
    REP32(DECLW)
#undef DECLW
    const float bh = bhh[g];

    if (g < D) {
        hf[g] = 0.f;
        h16[g] = (_Float16)0.f;
    }
    const float* xpb = xp + (size_t)b * SEQ * G3 + g;
    const float* xob = x + (size_t)b * SEQ * D + (g < D ? g : 0);
    float* xwb = x + (size_t)b * SEQ * D;
    __syncthreads();

    for (int t = 0; t < SEQ; ++t) {
        // prefetch (independent of h)
        float xpv = xpb[(size_t)t * G3];
        float xold = 0.f;
        if (g < D) xold = xob[(size_t)t * D];

        float acc0 = 0.f, acc1 = 0.f;
        const half8_t* hp = (const half8_t*)h16;
#define DOTB(n) { half8_t hv = hp[n]; \
        half2_t h0; h0.x = hv[0]; h0.y = hv[1]; \
        half2_t h1; h1.x = hv[2]; h1.y = hv[3]; \
        half2_t h2; h2.x = hv[4]; h2.y = hv[5]; \
        half2_t h3; h3.x = hv[6]; h3.y = hv[7]; \
        acc0 = fdot2_(u2h(W##n.x), h0, acc0); \
        acc1 = fdot2_(u2h(W##n.y), h1, acc1); \
        acc0 = fdot2_(u2h(W##n.z), h2, acc0); \
        acc1 = fdot2_(u2h(W##n.w), h3, acc1); }
        REP32(DOTB)
#undef DOTB

        float gv = acc0 + acc1 + bh;
        if (g < 2 * D) gv += xpv;          // fold x-part into r,z rows
        else xn_s[g - 2 * D] = xpv;        // n-row x-part kept separate
        gates[g] = gv;
        __syncthreads();

        if (g < D) {
            const int d = g;
            float r = 1.f / (1.f + expf(-gates[d]));
            float z = 1.f / (1.f + expf(-gates[D + d]));
            float n = tanhf(xn_s[d] + r * gates[2 * D + d]);
            float hold = hf[d];
            float hnew = (1.f - z) * n + z * hold;
            xwb[(size_t)t * D + d] = xold + hnew;
            hf[d] = hnew;
            h16[d] = (_Float16)hnew;
        }
        __syncthreads();
    }
}

// ---------------------------------------------------------------------------
// Kernel 5a: final LN + partial mean-pool (8 s-chunks per batch)
// part[b][c][d] = sum_{s in chunk c} (x[b,s,d]-mu)*rstd
// ---------------------------------------------------------------------------
__global__ __launch_bounds__(256) void pool_ln_part(
    const float* __restrict__ x, const float* __restrict__ st,
    float* __restrict__ part)
{
    const int b = blockIdx.x;
    const int c = blockIdx.y;
    const int d = threadIdx.x;
    float acc = 0.f;
    const int s0 = c * (SEQ / 8);
    for (int s = s0; s < s0 + SEQ / 8; ++s) {
        int m = b * SEQ + s;
        acc += (x[(size_t)m * D + d] - st[2 * m]) * st[2 * m + 1];
    }
    part[((size_t)b * 8 + c) * D + d] = acc;
}

// ---------------------------------------------------------------------------
// Kernel 5b: reduce partials + scale/bias -> emb
// ---------------------------------------------------------------------------
__global__ __launch_bounds__(256) void pool_ln_final(
    const float* __restrict__ part, const float* __restrict__ fsc,
    const float* __restrict__ fbi, float* __restrict__ emb)
{
    const int b = blockIdx.x;
    const int d = threadIdx.x;
    float acc = 0.f;
    #pragma unroll
    for (int c = 0; c < 8; ++c)
        acc += part[((size_t)b * 8 + c) * D + d];
    emb[b * D + d] = (acc * (1.f / (float)SEQ)) * fsc[d] + fbi[d];
}

// ---------------------------------------------------------------------------
// Kernel 6: classification head (tiny). Single block.
// ---------------------------------------------------------------------------
__global__ __launch_bounds__(256) void head_mlp(
    const float* __restrict__ emb, const float* __restrict__ w1,
    const float* __restrict__ b1, const float* __restrict__ w2,
    const float* __restrict__ b2, float* __restrict__ out)
{
    __shared__ float es[NB][D + 1];
    __shared__ float h1[NB][128 + 1];
    const int t = threadIdx.x;
    for (int i = t; i < NB * D; i += 256) es[i / D][i % D] = emb[i];
    __syncthreads();
    for (int i = t; i < NB * 128; i += 256) {
        int bb = i / 128, j = i % 128;
        float a = b1[j];
        for (int k = 0; k < D; ++k) a = fmaf(es[bb][k], w1[(size_t)k * 128 + j], a);
        h1[bb][j] = gelu_exact(a);
    }
    __syncthreads();
    for (int i = t; i < NB * 8; i += 256) {
        int bb = i / 8, c = i % 8;
        float a = b2[c];
        for (int k = 0; k < 128; ++k) a = fmaf(h1[bb][k], w2[(size_t)k * 8 + c], a);
        out[i] = a;
    }
}

// ---------------------------------------------------------------------------
extern "C" void kernel_launch(void* const* d_in, const int* in_sizes, int n_in,
                              void* d_out, int out_size, void* d_ws, size_t ws_size,
                              hipStream_t stream)
{
    const float* wav  = (const float*)d_in[0];
    const float* cw   = (const float*)d_in[1];
    const float* pos  = (const float*)d_in[2];
    const float* lnsc = (const float*)d_in[3];
    const float* lnbi = (const float*)d_in[4];
    const float* wih  = (const float*)d_in[5];
    const float* whh  = (const float*)d_in[6];
    const float* bih  = (const float*)d_in[7];
    const float* bhh  = (const float*)d_in[8];
    const float* fsc  = (const float*)d_in[9];
    const float* fbi  = (const float*)d_in[10];
    const float* hw1  = (const float*)d_in[11];
    const float* hb1  = (const float*)d_in[12];
    const float* hw2  = (const float*)d_in[13];
    const float* hb2  = (const float*)d_in[14];

    float* ws    = (float*)d_ws;
    float* x     = ws;                        // 8,192,000 f
    float* xp    = x + (size_t)M_TOTAL * D;   // 24,576,000 f
    float* st    = xp + (size_t)M_TOTAL * G3; // 64,000 f
    float* emb   = st + 2 * M_TOTAL;          // 8,192 f
    float* part  = emb + NB * D;              // 65,536 f
    _Float16* whh16 = (_Float16*)(part + NB * 8 * D); // 2.36 MB

    // one-shot weight conversion (re-done every call; ~10 us)
    {
        const int total4 = NL * G3 * D / 4;   // float4 count = 294912
        cvt_whh_fp16<<<total4 / 256, 256, 0, stream>>>(whh, whh16);
    }

    conv_gelu_pos<<<dim3(M_TOTAL / 64, D / 64), 256, 0, stream>>>(wav, cw, pos, x);

    for (int l = 0; l < NL; ++l) {
        row_stats<<<M_TOTAL, 64, 0, stream>>>(x, st);
        ln_xp_gemm<<<dim3(M_TOTAL / 64, G3 / 64), 256, 0, stream>>>(
            x, st, lnsc + (size_t)l * D, lnbi + (size_t)l * D,
            wih + (size_t)l * G3 * D, bih + (size_t)l * G3, xp);
        gru_scan_persist<<<NB, 768, 0, stream>>>(
            xp, whh16 + (size_t)l * G3 * D, bhh + (size_t)l * G3, x);
    }

    row_stats<<<M_TOTAL, 64, 0, stream>>>(x, st);
    pool_ln_part<<<dim3(NB, 8), 256, 0, stream>>>(x, st, part);
    pool_ln_final<<<NB, 256, 0, stream>>>(part, fsc, fbi, emb);
    head_mlp<<<1, 256, 0, stream>>>(emb, hw1, hb1, hw2, hb2, (float*)d_out);
}